// Round 5
// baseline (49.000 us; speedup 1.0000x reference)
//
#include <hip/hip_runtime.h>
#include <math.h>

constexpr int S   = 4096;
constexpr int L   = S - 1;     // 4095 returns
constexpr int H2  = 128;
constexpr int HID = 256;
constexpr int NPOS = 16;       // window positions per thread
constexpr int WMAX = 20;
constexpr int RMAX = NPOS + WMAX - 1;  // 35
constexpr float LN_EPS = 1e-5f;

__device__ __forceinline__ float fast_sqrt(float x)  { return __builtin_amdgcn_sqrtf(x); }
__device__ __forceinline__ float fast_rsqrt(float x) { return __builtin_amdgcn_rsqf(x); }

template<int W>
__device__ __forceinline__ float window_acc(const float (&rr)[RMAX], int t0,
                                            float s1, float s2) {
    // std = sqrt(s2*c1 - s1^2*c2), c1 = 1/(W-1), c2 = 1/(W*(W-1))
    constexpr float c1 = 1.f / (float)(W - 1);
    constexpr float c2 = 1.f / ((float)W * (float)(W - 1));
    const int n = L - W + 1;
    float acc = 0.f;
    if (t0 + NPOS <= n) {           // fast path: all 16 positions valid (255/256 threads)
        #pragma unroll
        for (int i = 0; i < NPOS; ++i) {
            float t = fmaf(-(s1 * c2), s1, s2 * c1);
            acc += fast_sqrt(fmaxf(t, 0.f));
            if (i < NPOS - 1) {
                float xin = rr[i + W], xout = rr[i];
                s1 += xin; s1 -= xout;
                s2 = fmaf(xin, xin, s2);
                s2 = fmaf(-xout, xout, s2);
            }
        }
    } else {                        // boundary path: last thread(s) only
        #pragma unroll
        for (int i = 0; i < NPOS; ++i) {
            float t  = fmaf(-(s1 * c2), s1, s2 * c1);
            float sd = fast_sqrt(fmaxf(t, 0.f));
            if (t0 + i < n) acc += sd;
            if (i < NPOS - 1) {
                float xin = rr[i + W], xout = rr[i];
                s1 += xin; s1 -= xout;
                s2 = fmaf(xin, xin, s2);
                s2 = fmaf(-xout, xout, s2);
            }
        }
    }
    return acc;
}

// ---------------- Kernel A: per-row volatility stats -> ws ----------------
__global__ __launch_bounds__(256)
void vol_stats(const float* __restrict__ prices, float* __restrict__ vols_out)
{
    __shared__ __align__(16) float lp[S + 40];
    __shared__ float redv[16];

    const int tid = threadIdx.x;
    const int b   = blockIdx.x;

    const float4* prow = reinterpret_cast<const float4*>(prices + (size_t)b * S);
    #pragma unroll
    for (int i = 0; i < 4; ++i) {
        int idx = tid + i * 256;
        float4 v = prow[idx];
        lp[idx * 4 + 0] = __logf(fmaxf(v.x, 1e-8f));
        lp[idx * 4 + 1] = __logf(fmaxf(v.y, 1e-8f));
        lp[idx * 4 + 2] = __logf(fmaxf(v.z, 1e-8f));
        lp[idx * 4 + 3] = __logf(fmaxf(v.w, 1e-8f));
    }
    if (tid < 40) lp[S + tid] = 0.f;
    __syncthreads();

    const int t0 = tid * NPOS;
    float lpv[36];
    #pragma unroll
    for (int j = 0; j < 9; ++j) {
        float4 v = *reinterpret_cast<const float4*>(&lp[t0 + 4 * j]);
        lpv[4 * j + 0] = v.x; lpv[4 * j + 1] = v.y;
        lpv[4 * j + 2] = v.z; lpv[4 * j + 3] = v.w;
    }
    float rr[RMAX];
    #pragma unroll
    for (int i = 0; i < RMAX; ++i) rr[i] = lpv[i + 1] - lpv[i];

    // shared window-sum inits: s(5) -> s(10) -> s(20)
    float s1a = 0.f, s2a = 0.f;
    #pragma unroll
    for (int j = 0; j < 5; ++j)  { s1a += rr[j]; s2a = fmaf(rr[j], rr[j], s2a); }
    float s1b = s1a, s2b = s2a;
    #pragma unroll
    for (int j = 5; j < 10; ++j) { s1b += rr[j]; s2b = fmaf(rr[j], rr[j], s2b); }
    float s1c = s1b, s2c = s2b;
    #pragma unroll
    for (int j = 10; j < 20; ++j){ s1c += rr[j]; s2c = fmaf(rr[j], rr[j], s2c); }

    float sum5  = window_acc<5>(rr, t0, s1a, s2a);
    float sum10 = window_acc<10>(rr, t0, s1b, s2b);
    float sum20 = window_acc<20>(rr, t0, s1c, s2c);

    #pragma unroll
    for (int off = 32; off; off >>= 1) {
        sum5  += __shfl_down(sum5,  off);
        sum10 += __shfl_down(sum10, off);
        sum20 += __shfl_down(sum20, off);
    }
    if ((tid & 63) == 0) {
        int w = tid >> 6;
        redv[w * 3 + 0] = sum5; redv[w * 3 + 1] = sum10; redv[w * 3 + 2] = sum20;
    }
    __syncthreads();
    if (tid < 3) {
        constexpr float sc[3] = { 1.f / (L - 5 + 1), 1.f / (L - 10 + 1), 1.f / (L - 20 + 1) };
        vols_out[b * 4 + tid] =
            (redv[tid] + redv[3 + tid] + redv[6 + tid] + redv[9 + tid]) * sc[tid];
    }
}

// ---------------- Kernel B: batched MLP, 4 rows per block ----------------
__global__ __launch_bounds__(256)
void mlp_batch(const float* __restrict__ vols,
               const float* __restrict__ W1,  const float* __restrict__ b1,
               const float* __restrict__ g1,  const float* __restrict__ be1,
               const float* __restrict__ W2,  const float* __restrict__ b2,
               const float* __restrict__ g2,  const float* __restrict__ be2,
               const float* __restrict__ Wc1, const float* __restrict__ bc1,
               const float* __restrict__ Wc2, const float* __restrict__ bc2,
               float* __restrict__ out_combined, float* __restrict__ out_regime)
{
    __shared__ float comb[4][HID];               // 4 KB: [h | h2f] per row
    __shared__ __align__(16) float partb[1024];  // 4 KB float4 partial scratch
    __shared__ float c1s[4][64];                 // 1 KB
    __shared__ float2 musig[4];
    __shared__ float lgt[16];
    __shared__ __align__(16) float vls[4][4];

    const int tid = threadIdx.x;
    const int r0  = blockIdx.x * 4;

    if (tid < 4)
        *reinterpret_cast<float4*>(vls[tid]) =
            reinterpret_cast<const float4*>(vols)[r0 + tid];
    __syncthreads();

    // ---- layer 1 + LN: c = tid&127, rows r2 and r2+2 ----
    const int c  = tid & 127;
    const int r2 = tid >> 7;
    const float w0 = W1[c], w1 = W1[H2 + c], w2 = W1[2 * H2 + c];
    const float bb1 = b1[c], gg1 = g1[c], ee1 = be1[c];
    float xa = fmaxf(fmaf(vls[r2][2],   w2, fmaf(vls[r2][1],   w1, fmaf(vls[r2][0],   w0, bb1))), 0.f);
    float xb = fmaxf(fmaf(vls[r2+2][2], w2, fmaf(vls[r2+2][1], w1, fmaf(vls[r2+2][0], w0, bb1))), 0.f);
    comb[r2][c] = xa; comb[r2 + 2][c] = xb;
    __syncthreads();
    {   // wave-per-row mean/rstd over 128
        const int r = tid >> 6, lane = tid & 63;
        float2 v = *reinterpret_cast<const float2*>(&comb[r][lane * 2]);
        float s = v.x + v.y, sq = v.x * v.x + v.y * v.y;
        #pragma unroll
        for (int off = 32; off; off >>= 1) { s += __shfl_down(s, off); sq += __shfl_down(sq, off); }
        if (lane == 0) {
            float mu = s * (1.f / H2);
            float var = sq * (1.f / H2) - mu * mu;
            musig[r] = make_float2(mu, fast_rsqrt(fmaxf(var, 0.f) + LN_EPS));
        }
    }
    __syncthreads();
    {
        float2 ma = musig[r2], mb = musig[r2 + 2];
        comb[r2][c]     = (xa - ma.x) * ma.y * gg1 + ee1;
        comb[r2 + 2][c] = (xb - mb.x) * mb.y * gg1 + ee1;
    }
    __syncthreads();

    // ---- layer 2 (128x128): q=tid&31 col-quad, r=(tid>>5)&3, h=tid>>7 k-half ----
    {
        const int q = tid & 31, r = (tid >> 5) & 3, h = tid >> 7;
        const float* wb = W2 + (size_t)(h * 64) * H2 + q * 4;
        float ax = 0.f, ay = 0.f, az = 0.f, aw = 0.f;
        #pragma unroll 8
        for (int k = 0; k < 64; ++k) {
            float a = comb[r][h * 64 + k];
            float4 w = *reinterpret_cast<const float4*>(wb + (size_t)k * H2);
            ax = fmaf(a, w.x, ax); ay = fmaf(a, w.y, ay);
            az = fmaf(a, w.z, az); aw = fmaf(a, w.w, aw);
        }
        reinterpret_cast<float4*>(partb)[tid] = make_float4(ax, ay, az, aw); // [h][r][q]
    }
    __syncthreads();
    float ya, yb;
    {
        const int qq = c >> 2, cc = c & 3;
        ya = fmaxf(partb[(0 * 128 + r2 * 32 + qq) * 4 + cc] +
                   partb[(1 * 128 + r2 * 32 + qq) * 4 + cc] + b2[c], 0.f);
        yb = fmaxf(partb[(0 * 128 + (r2 + 2) * 32 + qq) * 4 + cc] +
                   partb[(1 * 128 + (r2 + 2) * 32 + qq) * 4 + cc] + b2[c], 0.f);
        comb[r2][H2 + c] = ya; comb[r2 + 2][H2 + c] = yb;
    }
    __syncthreads();
    {   // LN over h2f
        const int r = tid >> 6, lane = tid & 63;
        float2 v = *reinterpret_cast<const float2*>(&comb[r][H2 + lane * 2]);
        float s = v.x + v.y, sq = v.x * v.x + v.y * v.y;
        #pragma unroll
        for (int off = 32; off; off >>= 1) { s += __shfl_down(s, off); sq += __shfl_down(sq, off); }
        if (lane == 0) {
            float mu = s * (1.f / H2);
            float var = sq * (1.f / H2) - mu * mu;
            musig[r] = make_float2(mu, fast_rsqrt(fmaxf(var, 0.f) + LN_EPS));
        }
    }
    __syncthreads();
    {
        const float gg2 = g2[c], ee2 = be2[c];
        float2 ma = musig[r2], mb = musig[r2 + 2];
        comb[r2][H2 + c]     = (ya - ma.x) * ma.y * gg2 + ee2;
        comb[r2 + 2][H2 + c] = (yb - mb.x) * mb.y * gg2 + ee2;
    }
    __syncthreads();

    // ---- classifier 256->64: cq=tid&15, r=(tid>>4)&3, quarter=tid>>6 ----
    {
        const int cq = tid & 15, r = (tid >> 4) & 3, qt = tid >> 6;
        const float* wb = Wc1 + (size_t)(qt * 64) * 64 + cq * 4;
        float ax = 0.f, ay = 0.f, az = 0.f, aw = 0.f;
        #pragma unroll 8
        for (int k = 0; k < 64; ++k) {
            float a = comb[r][qt * 64 + k];
            float4 w = *reinterpret_cast<const float4*>(wb + (size_t)k * 64);
            ax = fmaf(a, w.x, ax); ay = fmaf(a, w.y, ay);
            az = fmaf(a, w.z, az); aw = fmaf(a, w.w, aw);
        }
        reinterpret_cast<float4*>(partb)[tid] = make_float4(ax, ay, az, aw); // [qt][r][cq]
    }
    __syncthreads();
    {
        const int cc = tid & 63, r = tid >> 6;
        const int cq = cc >> 2, ci = cc & 3;
        float ssum = partb[(0 * 64 + r * 16 + cq) * 4 + ci] +
                     partb[(1 * 64 + r * 16 + cq) * 4 + ci] +
                     partb[(2 * 64 + r * 16 + cq) * 4 + ci] +
                     partb[(3 * 64 + r * 16 + cq) * 4 + ci];
        c1s[r][cc] = fmaxf(ssum + bc1[cc], 0.f);
    }
    __syncthreads();

    // ---- 64->4 logits (wave 0) + softmax ----
    if (tid < 64) {
        const int j = tid & 3, r = (tid >> 2) & 3, q4 = tid >> 4;
        float p = 0.f;
        #pragma unroll
        for (int k = 0; k < 16; ++k)
            p = fmaf(c1s[r][q4 * 16 + k], Wc2[(q4 * 16 + k) * 4 + j], p);
        p += __shfl_down(p, 32);
        p += __shfl_down(p, 16);
        if (tid < 16) lgt[tid] = p + bc2[j];
    }
    __syncthreads();
    if (tid < 4) {
        float l0 = lgt[tid * 4 + 0], l1 = lgt[tid * 4 + 1];
        float l2 = lgt[tid * 4 + 2], l3 = lgt[tid * 4 + 3];
        float m  = fmaxf(fmaxf(l0, l1), fmaxf(l2, l3));
        float e0 = __expf(l0 - m), e1 = __expf(l1 - m);
        float e2 = __expf(l2 - m), e3 = __expf(l3 - m);
        float inv = 1.f / (e0 + e1 + e2 + e3);
        reinterpret_cast<float4*>(out_regime)[r0 + tid] =
            make_float4(e0 * inv, e1 * inv, e2 * inv, e3 * inv);
    }

    // ---- write combined: r = tid>>6, c4 = tid&63 ----
    {
        const int r = tid >> 6, c4 = tid & 63;
        float4 v = *reinterpret_cast<const float4*>(&comb[r][c4 * 4]);
        reinterpret_cast<float4*>(out_combined)[(size_t)(r0 + r) * 64 + c4] = v;
    }
}

extern "C" void kernel_launch(void* const* d_in, const int* in_sizes, int n_in,
                              void* d_out, int out_size, void* d_ws, size_t ws_size,
                              hipStream_t stream) {
    const float* prices = (const float*)d_in[0];
    const float* W1  = (const float*)d_in[1];
    const float* b1  = (const float*)d_in[2];
    const float* g1  = (const float*)d_in[3];
    const float* be1 = (const float*)d_in[4];
    const float* W2  = (const float*)d_in[5];
    const float* b2  = (const float*)d_in[6];
    const float* g2  = (const float*)d_in[7];
    const float* be2 = (const float*)d_in[8];
    const float* Wc1 = (const float*)d_in[9];
    const float* bc1 = (const float*)d_in[10];
    const float* Wc2 = (const float*)d_in[11];
    const float* bc2 = (const float*)d_in[12];

    const int B = in_sizes[0] / S;                 // 4096
    float* out_combined = (float*)d_out;
    float* out_regime   = (float*)d_out + (size_t)B * HID;
    float* vols_ws      = (float*)d_ws;            // B*4 floats

    vol_stats<<<B, 256, 0, stream>>>(prices, vols_ws);
    mlp_batch<<<B / 4, 256, 0, stream>>>(vols_ws, W1, b1, g1, be1, W2, b2, g2, be2,
                                         Wc1, bc1, Wc2, bc2, out_combined, out_regime);
}

// Round 6
// 43.009 us; speedup vs baseline: 1.1393x; 1.1393x over previous
//
#include <hip/hip_runtime.h>
#include <math.h>

constexpr int S    = 4096;
constexpr int L    = S - 1;     // 4095 returns
constexpr int H2   = 128;
constexpr int HID  = 256;
constexpr int NPOS = 16;        // window positions per thread
constexpr int WMAX = 20;
constexpr int RMAX = NPOS + WMAX - 1;  // 35
constexpr int ROWS = 4;         // rows per block
constexpr float LN_EPS = 1e-5f;

__device__ __forceinline__ float fast_sqrt(float x)  { return __builtin_amdgcn_sqrtf(x); }
__device__ __forceinline__ float fast_rsqrt(float x) { return __builtin_amdgcn_rsqf(x); }

template<int W>
__device__ __forceinline__ float window_acc(const float (&rr)[RMAX], int t0,
                                            float s1, float s2) {
    // std = sqrt(s2*c1 - s1^2*c2), c1 = 1/(W-1), c2 = 1/(W*(W-1))
    constexpr float c1 = 1.f / (float)(W - 1);
    constexpr float c2 = 1.f / ((float)W * (float)(W - 1));
    const int n = L - W + 1;
    float acc = 0.f;
    if (t0 + NPOS <= n) {           // fast path: all 16 positions valid (255/256 threads)
        #pragma unroll
        for (int i = 0; i < NPOS; ++i) {
            float t = fmaf(-(s1 * c2), s1, s2 * c1);
            acc += fast_sqrt(fmaxf(t, 0.f));
            if (i < NPOS - 1) {
                float xin = rr[i + W], xout = rr[i];
                s1 += xin; s1 -= xout;
                s2 = fmaf(xin, xin, s2);
                s2 = fmaf(-xout, xout, s2);
            }
        }
    } else {                        // boundary path: last wave only
        #pragma unroll
        for (int i = 0; i < NPOS; ++i) {
            float t  = fmaf(-(s1 * c2), s1, s2 * c1);
            float sd = fast_sqrt(fmaxf(t, 0.f));
            if (t0 + i < n) acc += sd;
            if (i < NPOS - 1) {
                float xin = rr[i + W], xout = rr[i];
                s1 += xin; s1 -= xout;
                s2 = fmaf(xin, xin, s2);
                s2 = fmaf(-xout, xout, s2);
            }
        }
    }
    return acc;
}

__global__ __launch_bounds__(256)
void vol_fused4(const float* __restrict__ prices,
                const float* __restrict__ W1,  const float* __restrict__ b1,
                const float* __restrict__ g1,  const float* __restrict__ be1,
                const float* __restrict__ W2,  const float* __restrict__ b2,
                const float* __restrict__ g2,  const float* __restrict__ be2,
                const float* __restrict__ Wc1, const float* __restrict__ bc1,
                const float* __restrict__ Wc2, const float* __restrict__ bc2,
                float* __restrict__ out_combined, float* __restrict__ out_regime)
{
    __shared__ __align__(16) float lp[S + 40];   // log prices; reused as MLP scratch
    __shared__ float redv[16];
    __shared__ float vols_sh[ROWS][4];
    __shared__ float2 musig[ROWS];
    __shared__ float lgt[16];
    __shared__ float c1s[ROWS][64];

    // MLP scratch aliases lp (dead after the vol loop)
    float* fbuf  = lp;                 // comb: fbuf[r*HID + c], 1024 floats
    float* partb = lp + 4 * HID;       // 1024 floats, byte offset 4096 (16B aligned)

    const int tid = threadIdx.x;
    const int r0  = blockIdx.x * ROWS;

    if (tid < 40) lp[S + tid] = 0.f;   // pad once; rows never overwrite it

    // prefetch row 0 into registers
    const float4* prow = reinterpret_cast<const float4*>(prices + (size_t)r0 * S);
    float4 pf0 = prow[tid], pf1 = prow[tid + 256],
           pf2 = prow[tid + 512], pf3 = prow[tid + 768];

    // ================= vol loop: 4 rows sequentially =================
    #pragma unroll 1
    for (int r = 0; r < ROWS; ++r) {
        // issue next-row loads FIRST: latency hides under log+window compute
        float4 nf0, nf1, nf2, nf3;
        if (r < ROWS - 1) {
            const float4* nrow =
                reinterpret_cast<const float4*>(prices + (size_t)(r0 + r + 1) * S);
            nf0 = nrow[tid]; nf1 = nrow[tid + 256];
            nf2 = nrow[tid + 512]; nf3 = nrow[tid + 768];
        }

        // log(current row) -> LDS
        {
            float4 w;
            w.x = __logf(fmaxf(pf0.x, 1e-8f)); w.y = __logf(fmaxf(pf0.y, 1e-8f));
            w.z = __logf(fmaxf(pf0.z, 1e-8f)); w.w = __logf(fmaxf(pf0.w, 1e-8f));
            *reinterpret_cast<float4*>(&lp[(tid + 0) * 4]) = w;
            w.x = __logf(fmaxf(pf1.x, 1e-8f)); w.y = __logf(fmaxf(pf1.y, 1e-8f));
            w.z = __logf(fmaxf(pf1.z, 1e-8f)); w.w = __logf(fmaxf(pf1.w, 1e-8f));
            *reinterpret_cast<float4*>(&lp[(tid + 256) * 4]) = w;
            w.x = __logf(fmaxf(pf2.x, 1e-8f)); w.y = __logf(fmaxf(pf2.y, 1e-8f));
            w.z = __logf(fmaxf(pf2.z, 1e-8f)); w.w = __logf(fmaxf(pf2.w, 1e-8f));
            *reinterpret_cast<float4*>(&lp[(tid + 512) * 4]) = w;
            w.x = __logf(fmaxf(pf3.x, 1e-8f)); w.y = __logf(fmaxf(pf3.y, 1e-8f));
            w.z = __logf(fmaxf(pf3.z, 1e-8f)); w.w = __logf(fmaxf(pf3.w, 1e-8f));
            *reinterpret_cast<float4*>(&lp[(tid + 768) * 4]) = w;
        }
        __syncthreads();

        // sliding-window std sums for this row
        const int t0 = tid * NPOS;
        float lpv[36];
        #pragma unroll
        for (int j = 0; j < 9; ++j) {
            float4 v = *reinterpret_cast<const float4*>(&lp[t0 + 4 * j]);
            lpv[4 * j + 0] = v.x; lpv[4 * j + 1] = v.y;
            lpv[4 * j + 2] = v.z; lpv[4 * j + 3] = v.w;
        }
        float rr[RMAX];
        #pragma unroll
        for (int i = 0; i < RMAX; ++i) rr[i] = lpv[i + 1] - lpv[i];

        float s1a = 0.f, s2a = 0.f;
        #pragma unroll
        for (int j = 0; j < 5; ++j)  { s1a += rr[j]; s2a = fmaf(rr[j], rr[j], s2a); }
        float s1b = s1a, s2b = s2a;
        #pragma unroll
        for (int j = 5; j < 10; ++j) { s1b += rr[j]; s2b = fmaf(rr[j], rr[j], s2b); }
        float s1c = s1b, s2c = s2b;
        #pragma unroll
        for (int j = 10; j < 20; ++j){ s1c += rr[j]; s2c = fmaf(rr[j], rr[j], s2c); }

        float sum5  = window_acc<5>(rr, t0, s1a, s2a);
        float sum10 = window_acc<10>(rr, t0, s1b, s2b);
        float sum20 = window_acc<20>(rr, t0, s1c, s2c);

        #pragma unroll
        for (int off = 32; off; off >>= 1) {
            sum5  += __shfl_down(sum5,  off);
            sum10 += __shfl_down(sum10, off);
            sum20 += __shfl_down(sum20, off);
        }
        if ((tid & 63) == 0) {
            int w = tid >> 6;
            redv[w * 3 + 0] = sum5; redv[w * 3 + 1] = sum10; redv[w * 3 + 2] = sum20;
        }
        __syncthreads();   // redv ready; also: all lp reads done -> safe to overwrite
        if (tid < 3) {
            constexpr float sc[3] = { 1.f / (L - 5 + 1), 1.f / (L - 10 + 1), 1.f / (L - 20 + 1) };
            vols_sh[r][tid] =
                (redv[tid] + redv[3 + tid] + redv[6 + tid] + redv[9 + tid]) * sc[tid];
        }
        if (r < ROWS - 1) { pf0 = nf0; pf1 = nf1; pf2 = nf2; pf3 = nf3; }
    }
    __syncthreads();       // vols_sh ready; lp region now free for MLP scratch

    // ================= batched MLP for this block's 4 rows =================
    // ---- layer 1 + LN: c = tid&127, rows r2 and r2+2 ----
    const int c  = tid & 127;
    const int r2 = tid >> 7;
    const float w0 = W1[c], w1 = W1[H2 + c], w2 = W1[2 * H2 + c];
    const float bb1 = b1[c], gg1 = g1[c], ee1 = be1[c];
    float xa = fmaxf(fmaf(vols_sh[r2][2],   w2, fmaf(vols_sh[r2][1],   w1,
                     fmaf(vols_sh[r2][0],   w0, bb1))), 0.f);
    float xb = fmaxf(fmaf(vols_sh[r2+2][2], w2, fmaf(vols_sh[r2+2][1], w1,
                     fmaf(vols_sh[r2+2][0], w0, bb1))), 0.f);
    fbuf[r2 * HID + c] = xa; fbuf[(r2 + 2) * HID + c] = xb;
    __syncthreads();
    {   // wave-per-row mean/rstd over 128
        const int rw = tid >> 6, lane = tid & 63;
        float2 v = *reinterpret_cast<const float2*>(&fbuf[rw * HID + lane * 2]);
        float s = v.x + v.y, sq = v.x * v.x + v.y * v.y;
        #pragma unroll
        for (int off = 32; off; off >>= 1) { s += __shfl_down(s, off); sq += __shfl_down(sq, off); }
        if (lane == 0) {
            float mu = s * (1.f / H2);
            float var = sq * (1.f / H2) - mu * mu;
            musig[rw] = make_float2(mu, fast_rsqrt(fmaxf(var, 0.f) + LN_EPS));
        }
    }
    __syncthreads();
    {
        float2 ma = musig[r2], mb = musig[r2 + 2];
        fbuf[r2 * HID + c]       = (xa - ma.x) * ma.y * gg1 + ee1;
        fbuf[(r2 + 2) * HID + c] = (xb - mb.x) * mb.y * gg1 + ee1;
    }
    __syncthreads();

    // ---- layer 2 (128x128): q=tid&31 col-quad, rr4=(tid>>5)&3 row, h=tid>>7 k-half ----
    {
        const int q = tid & 31, rr4 = (tid >> 5) & 3, h = tid >> 7;
        const float* wb = W2 + (size_t)(h * 64) * H2 + q * 4;
        float ax = 0.f, ay = 0.f, az = 0.f, aw = 0.f;
        #pragma unroll 8
        for (int k = 0; k < 64; ++k) {
            float a = fbuf[rr4 * HID + h * 64 + k];
            float4 w = *reinterpret_cast<const float4*>(wb + (size_t)k * H2);
            ax = fmaf(a, w.x, ax); ay = fmaf(a, w.y, ay);
            az = fmaf(a, w.z, az); aw = fmaf(a, w.w, aw);
        }
        reinterpret_cast<float4*>(partb)[tid] = make_float4(ax, ay, az, aw); // [h][rr4][q]
    }
    __syncthreads();
    float ya, yb;
    {
        const int qq = c >> 2, cc = c & 3;
        ya = fmaxf(partb[(0 * 128 + r2 * 32 + qq) * 4 + cc] +
                   partb[(1 * 128 + r2 * 32 + qq) * 4 + cc] + b2[c], 0.f);
        yb = fmaxf(partb[(0 * 128 + (r2 + 2) * 32 + qq) * 4 + cc] +
                   partb[(1 * 128 + (r2 + 2) * 32 + qq) * 4 + cc] + b2[c], 0.f);
        fbuf[r2 * HID + H2 + c] = ya; fbuf[(r2 + 2) * HID + H2 + c] = yb;
    }
    __syncthreads();
    {   // LN over h2f
        const int rw = tid >> 6, lane = tid & 63;
        float2 v = *reinterpret_cast<const float2*>(&fbuf[rw * HID + H2 + lane * 2]);
        float s = v.x + v.y, sq = v.x * v.x + v.y * v.y;
        #pragma unroll
        for (int off = 32; off; off >>= 1) { s += __shfl_down(s, off); sq += __shfl_down(sq, off); }
        if (lane == 0) {
            float mu = s * (1.f / H2);
            float var = sq * (1.f / H2) - mu * mu;
            musig[rw] = make_float2(mu, fast_rsqrt(fmaxf(var, 0.f) + LN_EPS));
        }
    }
    __syncthreads();
    {
        const float gg2 = g2[c], ee2 = be2[c];
        float2 ma = musig[r2], mb = musig[r2 + 2];
        fbuf[r2 * HID + H2 + c]       = (ya - ma.x) * ma.y * gg2 + ee2;
        fbuf[(r2 + 2) * HID + H2 + c] = (yb - mb.x) * mb.y * gg2 + ee2;
    }
    __syncthreads();

    // ---- classifier 256->64: cq=tid&15, rr4=(tid>>4)&3, qt=tid>>6 k-quarter ----
    {
        const int cq = tid & 15, rr4 = (tid >> 4) & 3, qt = tid >> 6;
        const float* wb = Wc1 + (size_t)(qt * 64) * 64 + cq * 4;
        float ax = 0.f, ay = 0.f, az = 0.f, aw = 0.f;
        #pragma unroll 8
        for (int k = 0; k < 64; ++k) {
            float a = fbuf[rr4 * HID + qt * 64 + k];
            float4 w = *reinterpret_cast<const float4*>(wb + (size_t)k * 64);
            ax = fmaf(a, w.x, ax); ay = fmaf(a, w.y, ay);
            az = fmaf(a, w.z, az); aw = fmaf(a, w.w, aw);
        }
        reinterpret_cast<float4*>(partb)[tid] = make_float4(ax, ay, az, aw); // [qt][rr4][cq]
    }
    __syncthreads();
    {
        const int cc = tid & 63, rr4 = tid >> 6;
        const int cq = cc >> 2, ci = cc & 3;
        float ssum = partb[(0 * 64 + rr4 * 16 + cq) * 4 + ci] +
                     partb[(1 * 64 + rr4 * 16 + cq) * 4 + ci] +
                     partb[(2 * 64 + rr4 * 16 + cq) * 4 + ci] +
                     partb[(3 * 64 + rr4 * 16 + cq) * 4 + ci];
        c1s[rr4][cc] = fmaxf(ssum + bc1[cc], 0.f);
    }
    __syncthreads();

    // ---- 64->4 logits (wave 0) + softmax ----
    if (tid < 64) {
        const int j = tid & 3, rr4 = (tid >> 2) & 3, q4 = tid >> 4;
        float p = 0.f;
        #pragma unroll
        for (int k = 0; k < 16; ++k)
            p = fmaf(c1s[rr4][q4 * 16 + k], Wc2[(q4 * 16 + k) * 4 + j], p);
        p += __shfl_down(p, 32);
        p += __shfl_down(p, 16);
        if (tid < 16) lgt[tid] = p + bc2[j];
    }
    __syncthreads();
    if (tid < 4) {
        float l0 = lgt[tid * 4 + 0], l1 = lgt[tid * 4 + 1];
        float l2 = lgt[tid * 4 + 2], l3 = lgt[tid * 4 + 3];
        float m  = fmaxf(fmaxf(l0, l1), fmaxf(l2, l3));
        float e0 = __expf(l0 - m), e1 = __expf(l1 - m);
        float e2 = __expf(l2 - m), e3 = __expf(l3 - m);
        float inv = 1.f / (e0 + e1 + e2 + e3);
        reinterpret_cast<float4*>(out_regime)[r0 + tid] =
            make_float4(e0 * inv, e1 * inv, e2 * inv, e3 * inv);
    }

    // ---- write combined: r = tid>>6, c4 = tid&63 ----
    {
        const int rr4 = tid >> 6, c4 = tid & 63;
        float4 v = *reinterpret_cast<const float4*>(&fbuf[rr4 * HID + c4 * 4]);
        reinterpret_cast<float4*>(out_combined)[(size_t)(r0 + rr4) * 64 + c4] = v;
    }
}

extern "C" void kernel_launch(void* const* d_in, const int* in_sizes, int n_in,
                              void* d_out, int out_size, void* d_ws, size_t ws_size,
                              hipStream_t stream) {
    const float* prices = (const float*)d_in[0];
    const float* W1  = (const float*)d_in[1];
    const float* b1  = (const float*)d_in[2];
    const float* g1  = (const float*)d_in[3];
    const float* be1 = (const float*)d_in[4];
    const float* W2  = (const float*)d_in[5];
    const float* b2  = (const float*)d_in[6];
    const float* g2  = (const float*)d_in[7];
    const float* be2 = (const float*)d_in[8];
    const float* Wc1 = (const float*)d_in[9];
    const float* bc1 = (const float*)d_in[10];
    const float* Wc2 = (const float*)d_in[11];
    const float* bc2 = (const float*)d_in[12];

    const int B = in_sizes[0] / S;                 // 4096
    float* out_combined = (float*)d_out;
    float* out_regime   = (float*)d_out + (size_t)B * HID;

    vol_fused4<<<B / ROWS, 256, 0, stream>>>(prices, W1, b1, g1, be1, W2, b2, g2, be2,
                                             Wc1, bc1, Wc2, bc2, out_combined, out_regime);
}